// Round 4
// baseline (767.066 us; speedup 1.0000x reference)
//
#include <hip/hip_runtime.h>
#include <hip/hip_bf16.h>
#include <stdint.h>

// Problem dims (fixed by the reference)
constexpr int kB = 32;
constexpr int kS = 1024;
constexpr int kDin = 1024;
constexpr int kDout = 4096;
constexpr int kRank = 16;
constexpr int kNAdapt = 8;
constexpr int kM = kB * kS;     // 32768 rows
constexpr float kScale = 2.0f;  // alpha/rank = 32/16

typedef __attribute__((ext_vector_type(4))) float f32x4;
typedef __attribute__((ext_vector_type(8))) short s16x8;
typedef __attribute__((ext_vector_type(8))) unsigned short u16x8;
typedef __attribute__((ext_vector_type(4))) unsigned short u16x4;

__device__ __forceinline__ unsigned short f2bf(float f) {
  union { float f; uint32_t u; } x; x.f = f;
  uint32_t u = x.u;
  u += 0x7fffu + ((u >> 16) & 1u);   // round-to-nearest-even
  return (unsigned short)(u >> 16);
}

// ---------- Kernel 1: cast hidden_states f32 -> bf16 (vectorized 8/thread) ----------
__global__ void cast_h_kernel(const float* __restrict__ h, unsigned short* __restrict__ out) {
  size_t i = (size_t)blockIdx.x * blockDim.x + threadIdx.x;
  const f32x4* src = reinterpret_cast<const f32x4*>(h) + i * 2;
  f32x4 v0 = src[0], v1 = src[1];
  u16x8 r;
  r[0] = f2bf(v0[0]); r[1] = f2bf(v0[1]); r[2] = f2bf(v0[2]); r[3] = f2bf(v0[3]);
  r[4] = f2bf(v1[0]); r[5] = f2bf(v1[1]); r[6] = f2bf(v1[2]); r[7] = f2bf(v1[3]);
  *reinterpret_cast<u16x8*>(out + i * 8) = r;
}

// ---------- Kernel 2: LDS-tiled transpose + rank-16 update (R2, verified) ----------
__global__ __launch_bounds__(256) void build_weff_kernel(
    const float* __restrict__ W,
    const float* __restrict__ la,
    const float* __restrict__ lb,
    unsigned short* __restrict__ weff) {
  __shared__ float Wt[64][68];
  __shared__ float At[64][20];
  __shared__ float Bt[16][68];
  int bid = blockIdx.x;
  int e = bid & 7;
  int rem = bid >> 3;
  int dt = rem >> 6;
  int ot = rem & 63;
  int d0 = dt * 64, o0 = ot * 64;
  int t = threadIdx.x;
  {
    int r = t >> 4;
    int c = (t & 15) * 4;
    const float* wp = W + (size_t)(d0 + r) * kDout + o0 + c;
#pragma unroll
    for (int p = 0; p < 4; ++p) {
      f32x4 v = *reinterpret_cast<const f32x4*>(wp + (size_t)p * 16 * kDout);
      *reinterpret_cast<f32x4*>(&Wt[p * 16 + r][c]) = v;
    }
  }
  {
    int d = t >> 2, r4 = (t & 3) * 4;
    f32x4 v = *reinterpret_cast<const f32x4*>(la + ((size_t)e * kDin + d0 + d) * kRank + r4);
    *reinterpret_cast<f32x4*>(&At[d][r4]) = v;
  }
  {
    int r = t >> 4, c = (t & 15) * 4;
    f32x4 v = *reinterpret_cast<const f32x4*>(lb + ((size_t)e * kRank + r) * kDout + o0 + c);
    *reinterpret_cast<f32x4*>(&Bt[r][c]) = v;
  }
  __syncthreads();
  int ol_base = t >> 4;
  int dl = (t & 15) * 4;
  f32x4 areg[4][4];
#pragma unroll
  for (int j = 0; j < 4; ++j)
#pragma unroll
    for (int q = 0; q < 4; ++q)
      areg[j][q] = *reinterpret_cast<const f32x4*>(&At[dl + j][q * 4]);
#pragma unroll
  for (int p = 0; p < 4; ++p) {
    int ol = p * 16 + ol_base;
    float bv[kRank];
#pragma unroll
    for (int r = 0; r < kRank; ++r) bv[r] = Bt[r][ol];
    u16x4 r4;
#pragma unroll
    for (int j = 0; j < 4; ++j) {
      float acc = 0.f;
#pragma unroll
      for (int q = 0; q < 4; ++q)
        acc += areg[j][q][0] * bv[q * 4 + 0] + areg[j][q][1] * bv[q * 4 + 1] +
               areg[j][q][2] * bv[q * 4 + 2] + areg[j][q][3] * bv[q * 4 + 3];
      r4[j] = f2bf(Wt[dl + j][ol] + kScale * acc);
    }
    *reinterpret_cast<u16x4*>(weff + ((size_t)e * kDout + o0 + ol) * kDin + d0 + dl) = r4;
  }
}

// ---------- Kernel 3: persistent 256x256 8-phase grouped GEMM ----------
// 256 blocks (1/CU), each owns 8 output tiles: fixed mt (A-panel + aid reuse),
// nt = o8*8 + tt. The 8-phase counted-vmcnt pipeline runs continuously across
// tile boundaries (iter 7 stages the NEXT tile's K-tiles 0/1); epilogue stores
// drain under the next tile's first VMC(4).
constexpr int BM = 256, BN = 256, BK = 64;
constexpr int MT2 = kM / BM;      // 128
constexpr int NT2 = kDout / BN;   // 16
constexpr int TPB = 8;            // tiles per block
constexpr int NBLK = MT2 * NT2 / TPB;  // 256

__device__ __forceinline__ void gload16(const unsigned short* g, unsigned short* l) {
  __builtin_amdgcn_global_load_lds((const __attribute__((address_space(1))) void*)g,
                                   (__attribute__((address_space(3))) void*)l, 16, 0, 0);
}

// LDS element layout: slot*32768 + mat*16384 + half*8192 + instr*4096 + t*8
// logical (row r, elem c) lives at r*64 + (c ^ ((r&7)<<3)); source pre-swizzled.
#define STG_A2(slot, h, kk) do { \
  gload16(gA + (size_t)((h) * 128) * kDin + ((kk) & 15) * 64, ldst + (slot) * 32768 + (h) * 8192); \
  gload16(gA + (size_t)((h) * 128 + 64) * kDin + ((kk) & 15) * 64, ldst + (slot) * 32768 + (h) * 8192 + 4096); \
} while (0)
#define STG_B2(slot, h, kk, BP) do { \
  gload16((BP) + (size_t)((h) * 128) * kDin + ((kk) & 15) * 64, ldst + (slot) * 32768 + 16384 + (h) * 8192); \
  gload16((BP) + (size_t)((h) * 128 + 64) * kDin + ((kk) & 15) * 64, ldst + (slot) * 32768 + 16384 + (h) * 8192 + 4096); \
} while (0)

#define RD_A(mh) do { _Pragma("unroll") for (int ii = 0; ii < 4; ++ii) { \
  a[ii][0] = *(const s16x8*)&lds[sBase + aRow + ((mh) * 4 + ii) * 1024 + e0]; \
  a[ii][1] = *(const s16x8*)&lds[sBase + aRow + ((mh) * 4 + ii) * 1024 + e1]; } } while (0)
#define RD_B(nh, breg) do { _Pragma("unroll") for (int jj = 0; jj < 2; ++jj) { \
  breg[jj][0] = *(const s16x8*)&lds[sBase + bRow + ((nh) * 2 + jj) * 1024 + e0]; \
  breg[jj][1] = *(const s16x8*)&lds[sBase + bRow + ((nh) * 2 + jj) * 1024 + e1]; } } while (0)

#define MM(mh, nh, breg) do { \
  __builtin_amdgcn_s_setprio(1); \
  _Pragma("unroll") for (int ii = 0; ii < 4; ++ii) \
  _Pragma("unroll") for (int jj = 0; jj < 2; ++jj) { \
    acc[(mh) * 4 + ii][(nh) * 2 + jj] = __builtin_amdgcn_mfma_f32_16x16x32_bf16( \
        a[ii][0], breg[jj][0], acc[(mh) * 4 + ii][(nh) * 2 + jj], 0, 0, 0); \
    acc[(mh) * 4 + ii][(nh) * 2 + jj] = __builtin_amdgcn_mfma_f32_16x16x32_bf16( \
        a[ii][1], breg[jj][1], acc[(mh) * 4 + ii][(nh) * 2 + jj], 0, 0, 0); } \
  __builtin_amdgcn_s_setprio(0); \
} while (0)

#define BAR1() do { __builtin_amdgcn_sched_barrier(0); __builtin_amdgcn_s_barrier(); \
  asm volatile("s_waitcnt lgkmcnt(0)" ::: "memory"); __builtin_amdgcn_sched_barrier(0); } while (0)
#define BAR2() do { __builtin_amdgcn_sched_barrier(0); __builtin_amdgcn_s_barrier(); } while (0)
#define VMC(n) asm volatile("s_waitcnt vmcnt(" #n ")" ::: "memory")

__global__ __launch_bounds__(512, 2) void gemm256_kernel(
    const unsigned short* __restrict__ Ab,    // [M][K] bf16
    const unsigned short* __restrict__ Weff,  // [NA][N][K] bf16
    const float* __restrict__ bias,
    const int* __restrict__ aids,
    float* __restrict__ out) {
  __shared__ unsigned short lds[65536];   // 128 KiB
  int b = blockIdx.x;
  // same-XCD A-panel pairing: blocks b and b+8 share mt and land on one XCD
  int mt = (b & 7) * 16 + (b >> 4);       // 0..127
  int o8 = (b >> 3) & 1;                  // nt octet
  int aid = aids[mt >> 2];                // one sample per M-tile group
  const unsigned short* Aptr = Ab + (size_t)mt * BM * kDin;

  int t = threadIdx.x;
  int l = t & 63;
  int w = t >> 6;
  int wm = w >> 2;   // 0..1 (M)
  int wn = w & 3;    // 0..3 (N)

  // staging: thread t covers row t>>3 (per 64-row chunk), 16B col (t&7);
  // global source col pre-swizzled so LDS stays linear (rule #21)
  int srcColEl = ((t & 7) * 8) ^ (((t >> 3) & 7) << 3);
  const unsigned short* gA = Aptr + (size_t)(t >> 3) * kDin + srcColEl;
  const unsigned short* bP =
      Weff + ((size_t)aid * kDout + (size_t)(o8 * 8) * BN) * kDin +
      (size_t)(t >> 3) * kDin + srcColEl;
  constexpr size_t panelStride = (size_t)BN * kDin;   // 262144 elem
  unsigned short* ldst = lds + t * 8;

  // fragment-read addressing (element units)
  int xmEl = (l & 7) << 3;
  int e0 = (((l >> 4) * 8) ^ xmEl);
  int e1 = e0 ^ 32;
  int aRow = (wm * 128 + (l & 15)) * 64;
  int bRow = (wn * 64 + (l & 15)) * 64 + 16384;

  f32x4 acc[8][4];
#pragma unroll
  for (int m = 0; m < 8; ++m)
#pragma unroll
    for (int n = 0; n < 4; ++n) acc[m][n] = f32x4{0.f, 0.f, 0.f, 0.f};
  s16x8 a[4][2], b0[2][2], b1[2][2];

  // epilogue addressing
  size_t row0 = (size_t)mt * BM + wm * 128 + (l >> 4) * 4;
  int colBase = (o8 * 8) * BN + wn * 64 + (l & 15);
  size_t outOff = row0 * kDout + colBase;

  // prologue: tile0 kt0 full + kt1 half0s
  STG_B2(0, 0, 0, bP); STG_A2(0, 0, 0); STG_B2(0, 1, 0, bP); STG_A2(0, 1, 0);
  STG_B2(1, 0, 1, bP); STG_A2(1, 0, 1);
  VMC(4);
  BAR2();

#pragma unroll 1
  for (int tt = 0; tt < TPB; ++tt) {
    const unsigned short* bN = bP + panelStride;
    const bool lastTile = (tt == TPB - 1);
#pragma unroll
    for (int i = 0; i < 8; ++i) {
      const int kt1 = 2 * i + 1, kt2 = 2 * i + 2, kt3 = 2 * i + 3;
      const bool cross = (i == 7);           // kt2/kt3 belong to next tile
      // ph1
      { int sBase = 0; RD_A(0); RD_B(0, b0); }
      STG_B2(1, 1, kt1, bP);
      BAR1(); MM(0, 0, b0); BAR2();
      // ph2
      { int sBase = 0; RD_B(1, b1); }
      STG_A2(1, 1, kt1);
      BAR1(); MM(0, 1, b1); BAR2();
      // ph3
      { int sBase = 0; RD_A(1); }
      if (!cross) STG_B2(0, 0, kt2, bP);
      else if (!lastTile) STG_B2(0, 0, kt2, bN);
      BAR1(); MM(1, 0, b0); BAR2();
      // ph4
      if (!cross || !lastTile) { STG_A2(0, 0, kt2); VMC(4); }
      else { VMC(0); }
      BAR1(); MM(1, 1, b1); BAR2();
      // ph5
      { int sBase = 32768; RD_A(0); RD_B(0, b0); }
      if (!cross) STG_B2(0, 1, kt2, bP);
      else if (!lastTile) STG_B2(0, 1, kt2, bN);
      BAR1(); MM(0, 0, b0); BAR2();
      // ph6
      { int sBase = 32768; RD_B(1, b1); }
      if (!cross || !lastTile) STG_A2(0, 1, kt2);
      BAR1(); MM(0, 1, b1); BAR2();
      // ph7
      { int sBase = 32768; RD_A(1); }
      if (!cross) STG_B2(1, 0, kt3, bP);
      else if (!lastTile) STG_B2(1, 0, kt3, bN);
      BAR1(); MM(1, 0, b0); BAR2();
      // ph8
      if (!cross || !lastTile) { STG_A2(1, 0, kt3); VMC(4); }
      BAR1(); MM(1, 1, b1); BAR2();
    }
    // ---- epilogue for tile tt (stores drain under next tile's VMC(4)) ----
#pragma unroll
    for (int nf = 0; nf < 4; ++nf) {
      float bv = bias[colBase + tt * BN + nf * 16];
#pragma unroll
      for (int mf = 0; mf < 8; ++mf) {
#pragma unroll
        for (int j = 0; j < 4; ++j)
          out[outOff + (size_t)tt * BN + (size_t)(mf * 16 + j) * kDout + nf * 16] =
              acc[mf][nf][j] + bv;
      }
    }
    if (!lastTile) {
#pragma unroll
      for (int m = 0; m < 8; ++m)
#pragma unroll
        for (int n = 0; n < 4; ++n) acc[m][n] = f32x4{0.f, 0.f, 0.f, 0.f};
    }
    bP = bN;
  }
}

extern "C" void kernel_launch(void* const* d_in, const int* in_sizes, int n_in,
                              void* d_out, int out_size, void* d_ws, size_t ws_size,
                              hipStream_t stream) {
  const float* h    = (const float*)d_in[0];   // [32,1024,1024] f32
  const int*   aids = (const int*)d_in[1];     // [32] i32
  const float* W    = (const float*)d_in[2];   // [1024,4096] f32
  const float* bias = (const float*)d_in[3];   // [4096] f32
  const float* la   = (const float*)d_in[4];   // [8,1024,16] f32
  const float* lb   = (const float*)d_in[5];   // [8,16,4096] f32
  float* out = (float*)d_out;                  // [32,1024,4096] f32

  unsigned short* Abf  = (unsigned short*)d_ws;
  unsigned short* Weff = Abf + (size_t)kM * kDin;

  cast_h_kernel<<<(kM * (size_t)kDin / 8) / 256, 256, 0, stream>>>(h, Abf);
  build_weff_kernel<<<kNAdapt * (kDin / 64) * (kDout / 64), 256, 0, stream>>>(W, la, lb, Weff);
  gemm256_kernel<<<NBLK, 512, 0, stream>>>(Abf, Weff, bias, aids, out);
}

// Round 5
// 459.534 us; speedup vs baseline: 1.6692x; 1.6692x over previous
//
#include <hip/hip_runtime.h>
#include <hip/hip_bf16.h>
#include <stdint.h>

// Problem dims (fixed by the reference)
constexpr int kB = 32;
constexpr int kS = 1024;
constexpr int kDin = 1024;
constexpr int kDout = 4096;
constexpr int kRank = 16;
constexpr int kNAdapt = 8;
constexpr int kM = kB * kS;     // 32768 rows
constexpr float kScale = 2.0f;  // alpha/rank = 32/16

typedef __attribute__((ext_vector_type(4))) float f32x4;
typedef __attribute__((ext_vector_type(8))) short s16x8;
typedef __attribute__((ext_vector_type(8))) unsigned short u16x8;
typedef __attribute__((ext_vector_type(4))) unsigned short u16x4;

__device__ __forceinline__ unsigned short f2bf(float f) {
  union { float f; uint32_t u; } x; x.f = f;
  uint32_t u = x.u;
  u += 0x7fffu + ((u >> 16) & 1u);   // round-to-nearest-even
  return (unsigned short)(u >> 16);
}

// ---------- Kernel 1: cast hidden_states f32 -> bf16 (vectorized 8/thread) ----------
__global__ void cast_h_kernel(const float* __restrict__ h, unsigned short* __restrict__ out) {
  size_t i = (size_t)blockIdx.x * blockDim.x + threadIdx.x;
  const f32x4* src = reinterpret_cast<const f32x4*>(h) + i * 2;
  f32x4 v0 = src[0], v1 = src[1];
  u16x8 r;
  r[0] = f2bf(v0[0]); r[1] = f2bf(v0[1]); r[2] = f2bf(v0[2]); r[3] = f2bf(v0[3]);
  r[4] = f2bf(v1[0]); r[5] = f2bf(v1[1]); r[6] = f2bf(v1[2]); r[7] = f2bf(v1[3]);
  *reinterpret_cast<u16x8*>(out + i * 8) = r;
}

// ---------- Kernel 2: LDS-tiled transpose + rank-16 update (R2, verified) ----------
__global__ __launch_bounds__(256) void build_weff_kernel(
    const float* __restrict__ W,
    const float* __restrict__ la,
    const float* __restrict__ lb,
    unsigned short* __restrict__ weff) {
  __shared__ float Wt[64][68];
  __shared__ float At[64][20];
  __shared__ float Bt[16][68];
  int bid = blockIdx.x;
  int e = bid & 7;
  int rem = bid >> 3;
  int dt = rem >> 6;
  int ot = rem & 63;
  int d0 = dt * 64, o0 = ot * 64;
  int t = threadIdx.x;
  {
    int r = t >> 4;
    int c = (t & 15) * 4;
    const float* wp = W + (size_t)(d0 + r) * kDout + o0 + c;
#pragma unroll
    for (int p = 0; p < 4; ++p) {
      f32x4 v = *reinterpret_cast<const f32x4*>(wp + (size_t)p * 16 * kDout);
      *reinterpret_cast<f32x4*>(&Wt[p * 16 + r][c]) = v;
    }
  }
  {
    int d = t >> 2, r4 = (t & 3) * 4;
    f32x4 v = *reinterpret_cast<const f32x4*>(la + ((size_t)e * kDin + d0 + d) * kRank + r4);
    *reinterpret_cast<f32x4*>(&At[d][r4]) = v;
  }
  {
    int r = t >> 4, c = (t & 15) * 4;
    f32x4 v = *reinterpret_cast<const f32x4*>(lb + ((size_t)e * kRank + r) * kDout + o0 + c);
    *reinterpret_cast<f32x4*>(&Bt[r][c]) = v;
  }
  __syncthreads();
  int ol_base = t >> 4;
  int dl = (t & 15) * 4;
  f32x4 areg[4][4];
#pragma unroll
  for (int j = 0; j < 4; ++j)
#pragma unroll
    for (int q = 0; q < 4; ++q)
      areg[j][q] = *reinterpret_cast<const f32x4*>(&At[dl + j][q * 4]);
#pragma unroll
  for (int p = 0; p < 4; ++p) {
    int ol = p * 16 + ol_base;
    float bv[kRank];
#pragma unroll
    for (int r = 0; r < kRank; ++r) bv[r] = Bt[r][ol];
    u16x4 r4;
#pragma unroll
    for (int j = 0; j < 4; ++j) {
      float acc = 0.f;
#pragma unroll
      for (int q = 0; q < 4; ++q)
        acc += areg[j][q][0] * bv[q * 4 + 0] + areg[j][q][1] * bv[q * 4 + 1] +
               areg[j][q][2] * bv[q * 4 + 2] + areg[j][q][3] * bv[q * 4 + 3];
      r4[j] = f2bf(Wt[dl + j][ol] + kScale * acc);
    }
    *reinterpret_cast<u16x4*>(weff + ((size_t)e * kDout + o0 + ol) * kDin + d0 + dl) = r4;
  }
}

// ---------- Kernel 3: 256x256 8-phase grouped GEMM, A dbuf + B tribuf ----------
// LDS = A 2 slots (2x32KB) + B 3 slots (3x32KB) = 160 KiB exactly.
// B(kt+2) staged during tile kt's phases -> 5-7 phase stage-to-gate distance
// (covers HBM ~900cy latency); A stays 2-phase (L2-hot, 16 blocks/panel).
constexpr int BM = 256, BN = 256, BK = 64;
constexpr int MT2 = kM / BM;      // 128
constexpr int NT2 = kDout / BN;   // 16
constexpr int NWG2 = MT2 * NT2;   // 2048

__device__ __forceinline__ void gload16(const unsigned short* g, unsigned short* l) {
  __builtin_amdgcn_global_load_lds((const __attribute__((address_space(1))) void*)g,
                                   (__attribute__((address_space(3))) void*)l, 16, 0, 0);
}

// LDS elem layout: A slot sa in [0,2): sa*16384 + half*8192 + instr*4096 + t*8
//                  B slot sb in [0,3): 32768 + sb*16384 + half*8192 + instr*4096 + t*8
// logical (row r, elem c) lives at r*64 + (c ^ ((r&7)<<3)); source pre-swizzled.
#define STG_A3(sa, h, kk) do { \
  gload16(gA + (size_t)((h) * 128) * kDin + (kk) * 64, ldst + (sa) * 16384 + (h) * 8192); \
  gload16(gA + (size_t)((h) * 128 + 64) * kDin + (kk) * 64, ldst + (sa) * 16384 + (h) * 8192 + 4096); \
} while (0)
#define STG_B3(sb, h, kk) do { \
  gload16(gB + (size_t)((h) * 128) * kDin + (kk) * 64, ldst + 32768 + (sb) * 16384 + (h) * 8192); \
  gload16(gB + (size_t)((h) * 128 + 64) * kDin + (kk) * 64, ldst + 32768 + (sb) * 16384 + (h) * 8192 + 4096); \
} while (0)

#define RD_A(mh, sa) do { _Pragma("unroll") for (int ii = 0; ii < 4; ++ii) { \
  a[ii][0] = *(const s16x8*)&lds[(sa) * 16384 + aRow + ((mh) * 4 + ii) * 1024 + e0]; \
  a[ii][1] = *(const s16x8*)&lds[(sa) * 16384 + aRow + ((mh) * 4 + ii) * 1024 + e1]; } } while (0)
#define RD_B(nh, breg, sb) do { _Pragma("unroll") for (int jj = 0; jj < 2; ++jj) { \
  breg[jj][0] = *(const s16x8*)&lds[32768 + (sb) * 16384 + bRow + ((nh) * 2 + jj) * 1024 + e0]; \
  breg[jj][1] = *(const s16x8*)&lds[32768 + (sb) * 16384 + bRow + ((nh) * 2 + jj) * 1024 + e1]; } } while (0)

#define MM(mh, nh, breg) do { \
  __builtin_amdgcn_s_setprio(1); \
  _Pragma("unroll") for (int ii = 0; ii < 4; ++ii) \
  _Pragma("unroll") for (int jj = 0; jj < 2; ++jj) { \
    acc[(mh) * 4 + ii][(nh) * 2 + jj] = __builtin_amdgcn_mfma_f32_16x16x32_bf16( \
        a[ii][0], breg[jj][0], acc[(mh) * 4 + ii][(nh) * 2 + jj], 0, 0, 0); \
    acc[(mh) * 4 + ii][(nh) * 2 + jj] = __builtin_amdgcn_mfma_f32_16x16x32_bf16( \
        a[ii][1], breg[jj][1], acc[(mh) * 4 + ii][(nh) * 2 + jj], 0, 0, 0); } \
  __builtin_amdgcn_s_setprio(0); \
} while (0)

#define BAR1() do { __builtin_amdgcn_sched_barrier(0); __builtin_amdgcn_s_barrier(); \
  asm volatile("s_waitcnt lgkmcnt(0)" ::: "memory"); __builtin_amdgcn_sched_barrier(0); } while (0)
#define BAR2() do { __builtin_amdgcn_sched_barrier(0); __builtin_amdgcn_s_barrier(); } while (0)
#define VMC(n) asm volatile("s_waitcnt vmcnt(" #n ")" ::: "memory")

__global__ __launch_bounds__(512, 2) void gemm256_kernel(
    const unsigned short* __restrict__ Ab,    // [M][K] bf16
    const unsigned short* __restrict__ Weff,  // [NA][N][K] bf16
    const float* __restrict__ bias,
    const int* __restrict__ aids,
    float* __restrict__ out) {
  __shared__ unsigned short lds[81920];   // 160 KiB: A[2] + B[3] slots
  int bid = blockIdx.x;
  int swz = (bid & 7) * (NWG2 / 8) + (bid >> 3);   // XCD-aware, bijective
  int mt = swz >> 4, nt = swz & 15;
  int aid = aids[mt >> 2];   // BM=256 divides S=1024: one sample per M-tile
  const unsigned short* Aptr = Ab + (size_t)mt * BM * kDin;
  const unsigned short* Bptr = Weff + ((size_t)aid * kDout + (size_t)nt * BN) * kDin;

  int t = threadIdx.x;
  int l = t & 63;
  int w = t >> 6;
  int wm = w >> 2;   // 0..1 (M)
  int wn = w & 3;    // 0..3 (N)

  // staging: thread t covers row t>>3 (per 64-row chunk), 16B col (t&7);
  // global source col pre-swizzled so LDS stays linear (rule #21)
  int srcColEl = ((t & 7) * 8) ^ (((t >> 3) & 7) << 3);
  const unsigned short* gA = Aptr + (size_t)(t >> 3) * kDin + srcColEl;
  const unsigned short* gB = Bptr + (size_t)(t >> 3) * kDin + srcColEl;
  unsigned short* ldst = lds + t * 8;

  // fragment-read addressing (element units)
  int xmEl = (l & 7) << 3;
  int e0 = (((l >> 4) * 8) ^ xmEl);
  int e1 = e0 ^ 32;
  int aRow = (wm * 128 + (l & 15)) * 64;
  int bRow = (wn * 64 + (l & 15)) * 64;

  f32x4 acc[8][4];
#pragma unroll
  for (int m = 0; m < 8; ++m)
#pragma unroll
    for (int n = 0; n < 4; ++n) acc[m][n] = f32x4{0.f, 0.f, 0.f, 0.f};
  s16x8 a[4][2], b0[2][2], b1[2][2];

  // prologue: tiles 0 (A slot0, B slot0) and 1 (A slot1, B slot1); A1h1 comes
  // in iter0 ph2. VMC(6) drains exactly tile 0's 4 halves.
  STG_B3(0, 0, 0); STG_B3(0, 1, 0); STG_A3(0, 0, 0); STG_A3(0, 1, 0);
  STG_B3(1, 0, 1); STG_B3(1, 1, 1); STG_A3(1, 0, 1);
  VMC(6);
  BAR2();

#pragma unroll
  for (int i = 0; i < 8; ++i) {
    const int kt0 = 2 * i, kt1 = 2 * i + 1;
    const int sb0 = kt0 % 3, sb1 = kt1 % 3;
    const int sb2 = (kt0 + 2) % 3, sb3 = (kt1 + 2) % 3;
    const bool last = (i == 7);
    // ph1: read tile kt0 A(mh0)+B(nh0) | stage B(kt0+2) h0
    RD_A(0, 0); RD_B(0, b0, sb0);
    if (!last) STG_B3(sb2, 0, kt0 + 2);
    BAR1(); MM(0, 0, b0); BAR2();
    // ph2: read B(nh1) | stage A(kt1) h1
    RD_B(1, b1, sb0);
    STG_A3(1, 1, kt1);
    BAR1(); MM(0, 1, b1); BAR2();
    // ph3: read A(mh1) | stage B(kt0+2) h1
    RD_A(1, 0);
    if (!last) STG_B3(sb2, 1, kt0 + 2);
    BAR1(); MM(1, 0, b0); BAR2();
    // ph4: stage A(kt0+2) h0, gate tile kt1
    if (!last) { STG_A3(0, 0, kt0 + 2); VMC(4); } else { VMC(0); }
    BAR1(); MM(1, 1, b1); BAR2();
    // ph5: read tile kt1 A(mh0)+B(nh0) | stage B(kt1+2) h0
    RD_A(0, 1); RD_B(0, b0, sb1);
    if (!last) STG_B3(sb3, 0, kt1 + 2);
    BAR1(); MM(0, 0, b0); BAR2();
    // ph6: read B(nh1) | stage A(kt0+2) h1
    RD_B(1, b1, sb1);
    if (!last) STG_A3(0, 1, kt0 + 2);
    BAR1(); MM(0, 1, b1); BAR2();
    // ph7: read A(mh1) | stage B(kt1+2) h1
    RD_A(1, 1);
    if (!last) STG_B3(sb3, 1, kt1 + 2);
    BAR1(); MM(1, 0, b0); BAR2();
    // ph8: stage A(kt1+2) h0, gate tile kt0+2
    if (!last) { STG_A3(1, 0, kt1 + 2); VMC(4); }
    BAR1(); MM(1, 1, b1); BAR2();
  }

  // epilogue: C/D layout col = lane&15, row = (lane>>4)*4 + reg
  size_t row0 = (size_t)mt * BM + wm * 128 + (l >> 4) * 4;
  int col0 = nt * BN + wn * 64 + (l & 15);
#pragma unroll
  for (int nf = 0; nf < 4; ++nf) {
    float bv = bias[col0 + nf * 16];
#pragma unroll
    for (int mf = 0; mf < 8; ++mf) {
#pragma unroll
      for (int j = 0; j < 4; ++j)
        out[(row0 + mf * 16 + j) * kDout + col0 + nf * 16] = acc[mf][nf][j] + bv;
    }
  }
}

extern "C" void kernel_launch(void* const* d_in, const int* in_sizes, int n_in,
                              void* d_out, int out_size, void* d_ws, size_t ws_size,
                              hipStream_t stream) {
  const float* h    = (const float*)d_in[0];   // [32,1024,1024] f32
  const int*   aids = (const int*)d_in[1];     // [32] i32
  const float* W    = (const float*)d_in[2];   // [1024,4096] f32
  const float* bias = (const float*)d_in[3];   // [4096] f32
  const float* la   = (const float*)d_in[4];   // [8,1024,16] f32
  const float* lb   = (const float*)d_in[5];   // [8,16,4096] f32
  float* out = (float*)d_out;                  // [32,1024,4096] f32

  unsigned short* Abf  = (unsigned short*)d_ws;
  unsigned short* Weff = Abf + (size_t)kM * kDin;

  cast_h_kernel<<<(kM * (size_t)kDin / 8) / 256, 256, 0, stream>>>(h, Abf);
  build_weff_kernel<<<kNAdapt * (kDin / 64) * (kDout / 64), 256, 0, stream>>>(W, la, lb, Weff);
  gemm256_kernel<<<NWG2, 512, 0, stream>>>(Abf, Weff, bias, aids, out);
}

// Round 6
// 450.924 us; speedup vs baseline: 1.7011x; 1.0191x over previous
//
#include <hip/hip_runtime.h>
#include <hip/hip_bf16.h>
#include <stdint.h>

// Problem dims (fixed by the reference)
constexpr int kB = 32;
constexpr int kS = 1024;
constexpr int kDin = 1024;
constexpr int kDout = 4096;
constexpr int kRank = 16;
constexpr int kNAdapt = 8;
constexpr int kM = kB * kS;     // 32768 rows
constexpr float kScale = 2.0f;  // alpha/rank = 32/16

typedef __attribute__((ext_vector_type(4))) float f32x4;
typedef __attribute__((ext_vector_type(8))) short s16x8;
typedef __attribute__((ext_vector_type(8))) unsigned short u16x8;
typedef __attribute__((ext_vector_type(4))) unsigned short u16x4;

__device__ __forceinline__ unsigned short f2bf(float f) {
  union { float f; uint32_t u; } x; x.f = f;
  uint32_t u = x.u;
  u += 0x7fffu + ((u >> 16) & 1u);   // round-to-nearest-even
  return (unsigned short)(u >> 16);
}

// ---------- Kernel 1: cast hidden_states f32 -> bf16 (vectorized 8/thread) ----------
__global__ void cast_h_kernel(const float* __restrict__ h, unsigned short* __restrict__ out) {
  size_t i = (size_t)blockIdx.x * blockDim.x + threadIdx.x;
  const f32x4* src = reinterpret_cast<const f32x4*>(h) + i * 2;
  f32x4 v0 = src[0], v1 = src[1];
  u16x8 r;
  r[0] = f2bf(v0[0]); r[1] = f2bf(v0[1]); r[2] = f2bf(v0[2]); r[3] = f2bf(v0[3]);
  r[4] = f2bf(v1[0]); r[5] = f2bf(v1[1]); r[6] = f2bf(v1[2]); r[7] = f2bf(v1[3]);
  *reinterpret_cast<u16x8*>(out + i * 8) = r;
}

// ---------- Kernel 2: LDS-tiled transpose + rank-16 update (R2, verified) ----------
__global__ __launch_bounds__(256) void build_weff_kernel(
    const float* __restrict__ W,
    const float* __restrict__ la,
    const float* __restrict__ lb,
    unsigned short* __restrict__ weff) {
  __shared__ float Wt[64][68];
  __shared__ float At[64][20];
  __shared__ float Bt[16][68];
  int bid = blockIdx.x;
  int e = bid & 7;
  int rem = bid >> 3;
  int dt = rem >> 6;
  int ot = rem & 63;
  int d0 = dt * 64, o0 = ot * 64;
  int t = threadIdx.x;
  {
    int r = t >> 4;
    int c = (t & 15) * 4;
    const float* wp = W + (size_t)(d0 + r) * kDout + o0 + c;
#pragma unroll
    for (int p = 0; p < 4; ++p) {
      f32x4 v = *reinterpret_cast<const f32x4*>(wp + (size_t)p * 16 * kDout);
      *reinterpret_cast<f32x4*>(&Wt[p * 16 + r][c]) = v;
    }
  }
  {
    int d = t >> 2, r4 = (t & 3) * 4;
    f32x4 v = *reinterpret_cast<const f32x4*>(la + ((size_t)e * kDin + d0 + d) * kRank + r4);
    *reinterpret_cast<f32x4*>(&At[d][r4]) = v;
  }
  {
    int r = t >> 4, c = (t & 15) * 4;
    f32x4 v = *reinterpret_cast<const f32x4*>(lb + ((size_t)e * kRank + r) * kDout + o0 + c);
    *reinterpret_cast<f32x4*>(&Bt[r][c]) = v;
  }
  __syncthreads();
  int ol_base = t >> 4;
  int dl = (t & 15) * 4;
  f32x4 areg[4][4];
#pragma unroll
  for (int j = 0; j < 4; ++j)
#pragma unroll
    for (int q = 0; q < 4; ++q)
      areg[j][q] = *reinterpret_cast<const f32x4*>(&At[dl + j][q * 4]);
#pragma unroll
  for (int p = 0; p < 4; ++p) {
    int ol = p * 16 + ol_base;
    float bv[kRank];
#pragma unroll
    for (int r = 0; r < kRank; ++r) bv[r] = Bt[r][ol];
    u16x4 r4;
#pragma unroll
    for (int j = 0; j < 4; ++j) {
      float acc = 0.f;
#pragma unroll
      for (int q = 0; q < 4; ++q)
        acc += areg[j][q][0] * bv[q * 4 + 0] + areg[j][q][1] * bv[q * 4 + 1] +
               areg[j][q][2] * bv[q * 4 + 2] + areg[j][q][3] * bv[q * 4 + 3];
      r4[j] = f2bf(Wt[dl + j][ol] + kScale * acc);
    }
    *reinterpret_cast<u16x4*>(weff + ((size_t)e * kDout + o0 + ol) * kDin + d0 + dl) = r4;
  }
}

// ---------- Kernel 3: 256x256 grouped GEMM, 4-phase/iter, A dbuf + B tribuf ----------
// Phase = {ds_reads + 4 gloads -> barrier -> lgkm(0) -> 32 MFMA -> barrier}.
// Stage plan per iteration i (kt0=2i, kt1=2i+1):
//   P1: RD A(kt0,mh0)+B(kt0)      | STG A(kt1) h0+h1            (A slot1 free since i-1.P4)
//   P2: RD A(kt0,mh1)             | STG B(kt0+2) h0+h1 | VMC(4) gates {A(kt1),B(kt1)}
//   P3: RD A(kt1,mh0)+B(kt1)      | STG A(kt0+2) h0+h1          (A slot0 free since P2)
//   P4: RD A(kt1,mh1)             | STG B(kt1+2) h0+h1 | VMC(4) gates {A(kt0+2),B(kt0+2)}
// FIFO check: each VMC(4) keeps exactly the 4 gloads of its own phase.
constexpr int BM = 256, BN = 256, BK = 64;
constexpr int MT2 = kM / BM;      // 128
constexpr int NT2 = kDout / BN;   // 16
constexpr int NWG2 = MT2 * NT2;   // 2048

__device__ __forceinline__ void gload16(const unsigned short* g, unsigned short* l) {
  __builtin_amdgcn_global_load_lds((const __attribute__((address_space(1))) void*)g,
                                   (__attribute__((address_space(3))) void*)l, 16, 0, 0);
}

// LDS elem layout: A slot sa in [0,2): sa*16384 + half*8192 + instr*4096 + t*8
//                  B slot sb in [0,3): 32768 + sb*16384 + half*8192 + instr*4096 + t*8
// logical (row r, elem c) lives at r*64 + (c ^ ((r&7)<<3)); source pre-swizzled.
#define STG_A3(sa, kk) do { \
  gload16(gA + (size_t)0 * kDin + (kk) * 64, ldst + (sa) * 16384); \
  gload16(gA + (size_t)64 * kDin + (kk) * 64, ldst + (sa) * 16384 + 4096); \
  gload16(gA + (size_t)128 * kDin + (kk) * 64, ldst + (sa) * 16384 + 8192); \
  gload16(gA + (size_t)192 * kDin + (kk) * 64, ldst + (sa) * 16384 + 12288); \
} while (0)
#define STG_B3(sb, kk) do { \
  gload16(gB + (size_t)0 * kDin + (kk) * 64, ldst + 32768 + (sb) * 16384); \
  gload16(gB + (size_t)64 * kDin + (kk) * 64, ldst + 32768 + (sb) * 16384 + 4096); \
  gload16(gB + (size_t)128 * kDin + (kk) * 64, ldst + 32768 + (sb) * 16384 + 8192); \
  gload16(gB + (size_t)192 * kDin + (kk) * 64, ldst + 32768 + (sb) * 16384 + 12288); \
} while (0)

#define RD_A(mh, sa) do { _Pragma("unroll") for (int ii = 0; ii < 4; ++ii) { \
  a[ii][0] = *(const s16x8*)&lds[(sa) * 16384 + aRow + ((mh) * 4 + ii) * 1024 + e0]; \
  a[ii][1] = *(const s16x8*)&lds[(sa) * 16384 + aRow + ((mh) * 4 + ii) * 1024 + e1]; } } while (0)
#define RD_B(nh, breg, sb) do { _Pragma("unroll") for (int jj = 0; jj < 2; ++jj) { \
  breg[jj][0] = *(const s16x8*)&lds[32768 + (sb) * 16384 + bRow + ((nh) * 2 + jj) * 1024 + e0]; \
  breg[jj][1] = *(const s16x8*)&lds[32768 + (sb) * 16384 + bRow + ((nh) * 2 + jj) * 1024 + e1]; } } while (0)

#define MMQ(mh, nh, breg) do { \
  _Pragma("unroll") for (int ii = 0; ii < 4; ++ii) \
  _Pragma("unroll") for (int jj = 0; jj < 2; ++jj) { \
    acc[(mh) * 4 + ii][(nh) * 2 + jj] = __builtin_amdgcn_mfma_f32_16x16x32_bf16( \
        a[ii][0], breg[jj][0], acc[(mh) * 4 + ii][(nh) * 2 + jj], 0, 0, 0); \
    acc[(mh) * 4 + ii][(nh) * 2 + jj] = __builtin_amdgcn_mfma_f32_16x16x32_bf16( \
        a[ii][1], breg[jj][1], acc[(mh) * 4 + ii][(nh) * 2 + jj], 0, 0, 0); } \
} while (0)

#define MM2(mh) do { \
  __builtin_amdgcn_s_setprio(1); \
  MMQ(mh, 0, b0); MMQ(mh, 1, b1); \
  __builtin_amdgcn_s_setprio(0); \
} while (0)

#define BAR1() do { __builtin_amdgcn_sched_barrier(0); __builtin_amdgcn_s_barrier(); \
  asm volatile("s_waitcnt lgkmcnt(0)" ::: "memory"); __builtin_amdgcn_sched_barrier(0); } while (0)
#define BAR2() do { __builtin_amdgcn_sched_barrier(0); __builtin_amdgcn_s_barrier(); } while (0)
#define VMC(n) asm volatile("s_waitcnt vmcnt(" #n ")" ::: "memory")

__global__ __launch_bounds__(512, 2) void gemm256_kernel(
    const unsigned short* __restrict__ Ab,    // [M][K] bf16
    const unsigned short* __restrict__ Weff,  // [NA][N][K] bf16
    const float* __restrict__ bias,
    const int* __restrict__ aids,
    float* __restrict__ out) {
  __shared__ unsigned short lds[81920];   // 160 KiB: A[2] + B[3] slots
  int bid = blockIdx.x;
  int swz = (bid & 7) * (NWG2 / 8) + (bid >> 3);   // XCD-aware, bijective
  int mt = swz >> 4, nt = swz & 15;
  int aid = aids[mt >> 2];   // BM=256 divides S=1024: one sample per M-tile
  const unsigned short* Aptr = Ab + (size_t)mt * BM * kDin;
  const unsigned short* Bptr = Weff + ((size_t)aid * kDout + (size_t)nt * BN) * kDin;

  int t = threadIdx.x;
  int l = t & 63;
  int w = t >> 6;
  int wm = w >> 2;   // 0..1 (M)
  int wn = w & 3;    // 0..3 (N)

  // staging: thread t covers row t>>3 (per 64-row chunk), 16B col (t&7);
  // global source col pre-swizzled so LDS stays linear (rule #21)
  int srcColEl = ((t & 7) * 8) ^ (((t >> 3) & 7) << 3);
  const unsigned short* gA = Aptr + (size_t)(t >> 3) * kDin + srcColEl;
  const unsigned short* gB = Bptr + (size_t)(t >> 3) * kDin + srcColEl;
  unsigned short* ldst = lds + t * 8;

  // fragment-read addressing (element units)
  int xmEl = (l & 7) << 3;
  int e0 = (((l >> 4) * 8) ^ xmEl);
  int e1 = e0 ^ 32;
  int aRow = (wm * 128 + (l & 15)) * 64;
  int bRow = (wn * 64 + (l & 15)) * 64;

  f32x4 acc[8][4];
#pragma unroll
  for (int m = 0; m < 8; ++m)
#pragma unroll
    for (int n = 0; n < 4; ++n) acc[m][n] = f32x4{0.f, 0.f, 0.f, 0.f};
  s16x8 a[4][2], b0[2][2], b1[2][2];

  // prologue: B(0), A(0), B(1); VMC(4) keeps B(1), drains B(0)+A(0)
  STG_B3(0, 0); STG_A3(0, 0); STG_B3(1, 1);
  VMC(4);
  BAR2();

#pragma unroll
  for (int i = 0; i < 8; ++i) {
    const int kt0 = 2 * i, kt1 = 2 * i + 1;
    const int sb0 = kt0 % 3, sb1 = kt1 % 3;
    const int sb2 = (kt0 + 2) % 3, sb3 = (kt1 + 2) % 3;
    const bool last = (i == 7);
    // P1: read kt0 (mh0) + B(kt0); stage A(kt1) into slot1 (free since i-1.P4)
    RD_A(0, 0); RD_B(0, b0, sb0); RD_B(1, b1, sb0);
    STG_A3(1, kt1);
    BAR1(); MM2(0); BAR2();
    // P2: read kt0 (mh1); stage B(kt0+2); gate {A(kt1), B(kt1)}
    RD_A(1, 0);
    if (!last) { STG_B3(sb2, kt0 + 2); VMC(4); } else { VMC(0); }
    BAR1(); MM2(1); BAR2();
    // P3: read kt1 (mh0) + B(kt1); stage A(kt0+2) into slot0 (free since P2)
    RD_A(0, 1); RD_B(0, b0, sb1); RD_B(1, b1, sb1);
    if (!last) STG_A3(0, kt0 + 2);
    BAR1(); MM2(0); BAR2();
    // P4: read kt1 (mh1); stage B(kt1+2); gate {A(kt0+2), B(kt0+2)}
    RD_A(1, 1);
    if (!last) { STG_B3(sb3, kt1 + 2); VMC(4); }
    BAR1(); MM2(1); BAR2();
  }

  // epilogue: C/D layout col = lane&15, row = (lane>>4)*4 + reg
  size_t row0 = (size_t)mt * BM + wm * 128 + (l >> 4) * 4;
  int col0 = nt * BN + wn * 64 + (l & 15);
#pragma unroll
  for (int nf = 0; nf < 4; ++nf) {
    float bv = bias[col0 + nf * 16];
#pragma unroll
    for (int mf = 0; mf < 8; ++mf) {
#pragma unroll
      for (int j = 0; j < 4; ++j)
        out[(row0 + mf * 16 + j) * kDout + col0 + nf * 16] = acc[mf][nf][j] + bv;
    }
  }
}

extern "C" void kernel_launch(void* const* d_in, const int* in_sizes, int n_in,
                              void* d_out, int out_size, void* d_ws, size_t ws_size,
                              hipStream_t stream) {
  const float* h    = (const float*)d_in[0];   // [32,1024,1024] f32
  const int*   aids = (const int*)d_in[1];     // [32] i32
  const float* W    = (const float*)d_in[2];   // [1024,4096] f32
  const float* bias = (const float*)d_in[3];   // [4096] f32
  const float* la   = (const float*)d_in[4];   // [8,1024,16] f32
  const float* lb   = (const float*)d_in[5];   // [8,16,4096] f32
  float* out = (float*)d_out;                  // [32,1024,4096] f32

  unsigned short* Abf  = (unsigned short*)d_ws;
  unsigned short* Weff = Abf + (size_t)kM * kDin;

  cast_h_kernel<<<(kM * (size_t)kDin / 8) / 256, 256, 0, stream>>>(h, Abf);
  build_weff_kernel<<<kNAdapt * (kDin / 64) * (kDout / 64), 256, 0, stream>>>(W, la, lb, Weff);
  gemm256_kernel<<<NWG2, 512, 0, stream>>>(Abf, Weff, bias, aids, out);
}